// Round 2
// baseline (2521.737 us; speedup 1.0000x reference)
//
#include <hip/hip_runtime.h>

// ============================================================================
// MoE SparseDispatcher (B=4,S=2048,D=1024,H=4096,DO=1024,E=8,K=2,cap=1536)
// Round 2: same pipeline as R1; MFMA fragment type switched to short8 (the
// compile-verified gfx950 form per the guide) to remove compile risk.
// Expert GEMMs via bf16 hi/lo split (3 MFMA products = fp32-quality).
// m97-style 128x128 MFMA tiles, BK=32, global_load_lds staging, XOR-swizzled
// LDS fragment reads. Dynamic expert-grouping G in {8,4,2,1} from ws_size.
// ============================================================================

typedef unsigned short u16;
typedef unsigned int   u32;
typedef short bf16x8 __attribute__((ext_vector_type(8)));   // 8 bf16 bit patterns
typedef float f32x4  __attribute__((ext_vector_type(4)));

constexpr int NTOK = 4 * 2048;   // 8192 tokens
constexpr int DIN  = 1024;
constexpr int HID  = 4096;
constexpr int DOUT = 1024;
constexpr int NE   = 8;
constexpr int TOPK = 2;
constexpr int CAP  = 1536;       // max(int(8192*1.5/8), 2)

__device__ __forceinline__ u16 f2bf(float f) {          // round-to-nearest-even
  u32 u = __float_as_uint(f);
  u32 r = u + 0x7FFFu + ((u >> 16) & 1u);
  return (u16)(r >> 16);
}
__device__ __forceinline__ float bf2f(u16 h) {
  return __uint_as_float(((u32)h) << 16);
}
__device__ __forceinline__ void gload16(const u16* g, u16* l) {
  __builtin_amdgcn_global_load_lds(
      (const __attribute__((address_space(1))) void*)g,
      (__attribute__((address_space(3))) void*)l, 16, 0, 0);
}

// ---------------------------------------------------------------------------
// 1) Router: logits = x@rw + rb; softmax; top-2 (ties -> lower index, matches
//    lax.top_k); renormalized weights. One block per token.
// ---------------------------------------------------------------------------
__global__ __launch_bounds__(256) void router_topk(
    const float* __restrict__ x, const float* __restrict__ rw,
    const float* __restrict__ rb, int* __restrict__ topi, float* __restrict__ topv)
{
  const int n = blockIdx.x, tid = threadIdx.x, lane = tid & 63, wid = tid >> 6;
  float p[NE] = {0.f,0.f,0.f,0.f,0.f,0.f,0.f,0.f};
  const float* xr = x + (size_t)n * DIN;
  for (int d = tid; d < DIN; d += 256) {
    float xv = xr[d];
    const float* rwd = rw + d * NE;
#pragma unroll
    for (int e = 0; e < NE; e++) p[e] += xv * rwd[e];
  }
#pragma unroll
  for (int e = 0; e < NE; e++)
    for (int o = 32; o; o >>= 1) p[e] += __shfl_down(p[e], o, 64);
  __shared__ float red[4][NE];
  if (lane == 0) {
#pragma unroll
    for (int e = 0; e < NE; e++) red[wid][e] = p[e];
  }
  __syncthreads();
  if (tid == 0) {
    float l[NE], mx = -1e30f;
#pragma unroll
    for (int e = 0; e < NE; e++) {
      l[e] = red[0][e] + red[1][e] + red[2][e] + red[3][e] + rb[e];
      mx = fmaxf(mx, l[e]);
    }
    float s = 0.f, pr[NE];
#pragma unroll
    for (int e = 0; e < NE; e++) { pr[e] = expf(l[e] - mx); s += pr[e]; }
#pragma unroll
    for (int e = 0; e < NE; e++) pr[e] /= s;
    int i0 = 0; float v0 = pr[0];
    for (int e = 1; e < NE; e++) if (pr[e] > v0) { v0 = pr[e]; i0 = e; }
    int i1 = -1; float v1 = -1.f;
    for (int e = 0; e < NE; e++) if (e != i0 && pr[e] > v1) { v1 = pr[e]; i1 = e; }
    float sum = v0 + v1;
    topi[2*n] = i0; topi[2*n+1] = i1;
    topv[2*n] = v0 / sum; topv[2*n+1] = v1 / sum;
  }
}

// ---------------------------------------------------------------------------
// 2) Exact per-expert capacity threshold: radix-select (MSB->LSB, 4 bytes) on
//    positive-float bit patterns (order-isomorphic to float order). Outputs
//    the CAP-th largest value's bits and how many tied-at-threshold entries
//    to keep (ties -> ascending flat index, matching lax.top_k).
//    keep-all case: t_bits=0, ntie=0 (all v>0 pass).
// ---------------------------------------------------------------------------
__global__ void select_caps(const int* __restrict__ topi, const float* __restrict__ topv,
                            u32* __restrict__ t_bits, int* __restrict__ ntie)
{
  const int e = blockIdx.x, tid = threadIdx.x;
  __shared__ u32 hist[256];
  __shared__ u32 s_prefix;
  __shared__ int s_rank, s_done;
  if (tid == 0) { s_prefix = 0u; s_rank = CAP; s_done = 0; }
  __syncthreads();
  for (int byte = 3; byte >= 0; --byte) {
    hist[tid] = 0u;
    __syncthreads();
    const u32 pfx = s_prefix;
    const u32 him = (byte == 3) ? 0u : (0xFFFFFFFFu << ((byte + 1) * 8));
    for (int f = tid; f < NTOK * TOPK; f += 256) {
      if (topi[f] == e) {
        u32 u = __float_as_uint(topv[f]);
        if ((u & him) == pfx) atomicAdd(&hist[(u >> (byte * 8)) & 255u], 1u);
      }
    }
    __syncthreads();
    if (tid == 0) {
      if (byte == 3) {
        int total = 0;
        for (int b = 0; b < 256; b++) total += (int)hist[b];
        if (total <= CAP) { t_bits[e] = 0u; ntie[e] = 0; s_done = 1; }
      }
      if (!s_done) {
        int R = s_rank, cum = 0, b;
        for (b = 255; b >= 0; --b) { cum += (int)hist[b]; if (cum >= R) break; }
        s_prefix = s_prefix | (((u32)b) << (byte * 8));
        s_rank = R - (cum - (int)hist[b]);
      }
    }
    __syncthreads();
    if (s_done) return;
  }
  if (tid == 0) { t_bits[e] = s_prefix; ntie[e] = s_rank; }
}

// ---------------------------------------------------------------------------
// 3) Assign kept (token,k) pairs to expert slots (order within expert is
//    irrelevant downstream). slot_of_token[f] = slot or -1.
// ---------------------------------------------------------------------------
__global__ void assign_slots(const int* __restrict__ topi, const float* __restrict__ topv,
                             const u32* __restrict__ tb, const int* __restrict__ ntie,
                             int* __restrict__ cnt, int* __restrict__ tok,
                             float* __restrict__ wsl, int* __restrict__ s_of_t)
{
  const int f = blockIdx.x * 256 + threadIdx.x;
  const int e = topi[f];
  const float v = topv[f];
  const u32 vb = __float_as_uint(v);
  const u32 t = tb[e];
  bool keep = vb > t;
  if (!keep && vb == t) {           // rare: tied at threshold -> rank by index
    int rank = 0;
    for (int g = 0; g < f; g++)
      if (topi[g] == e && __float_as_uint(topv[g]) == vb) rank++;
    keep = rank < ntie[e];
  }
  int sl = -1;
  if (keep) {
    int c = atomicAdd(&cnt[e], 1);
    sl = e * CAP + c;
    tok[sl] = f >> 1;
    wsl[sl] = v;
  }
  s_of_t[f] = sl;
}

// ---------------------------------------------------------------------------
// 4) Gather token rows -> Xe bf16 hi/lo planes [E*CAP][DIN]; pad rows zeroed.
// ---------------------------------------------------------------------------
__global__ __launch_bounds__(256) void gather_x(
    const float* __restrict__ x, const int* __restrict__ tok, const int* __restrict__ cnt,
    u16* __restrict__ Xh, u16* __restrict__ Xl)
{
  const int slot = blockIdx.x;
  const int e = slot / CAP, c = slot % CAP;
  const int tid = threadIdx.x;
  const size_t ob = (size_t)slot * DIN + tid * 4;
  ushort4 h4, l4;
  if (c < cnt[e]) {
    const int n = tok[slot];
    const float4 v = *(const float4*)(x + (size_t)n * DIN + tid * 4);
    u16 h, l;
    h = f2bf(v.x); l = f2bf(v.x - bf2f(h)); h4.x = h; l4.x = l;
    h = f2bf(v.y); l = f2bf(v.y - bf2f(h)); h4.y = h; l4.y = l;
    h = f2bf(v.z); l = f2bf(v.z - bf2f(h)); h4.z = h; l4.z = l;
    h = f2bf(v.w); l = f2bf(v.w - bf2f(h)); h4.w = h; l4.w = l;
  } else {
    h4.x = h4.y = h4.z = h4.w = 0; l4 = h4;
  }
  *(ushort4*)(Xh + ob) = h4;
  *(ushort4*)(Xl + ob) = l4;
}

// ---------------------------------------------------------------------------
// 5) Transpose+split weights: in [E][R][C] fp32 (expert e_off+z) -> out
//    [z][C][R] bf16 hi/lo. 64x64 tiles via LDS (stride 65: conflict-free).
// ---------------------------------------------------------------------------
__global__ __launch_bounds__(256) void transpose_split(
    const float* __restrict__ in, u16* __restrict__ oh, u16* __restrict__ ol,
    int R, int C, int e_off)
{
  const int z = blockIdx.z, e = e_off + z;
  const int c0 = blockIdx.x * 64, r0 = blockIdx.y * 64;
  const int tid = threadIdx.x;
  const int rr = tid >> 4;          // 0..15
  const int cc = (tid & 15) * 4;    // 0..60
  __shared__ float t[64][65];
  const float* ibase = in + (size_t)e * R * C;
#pragma unroll
  for (int q = 0; q < 4; q++) {
    const float4 v = *(const float4*)(ibase + (size_t)(r0 + q * 16 + rr) * C + c0 + cc);
    t[q * 16 + rr][cc + 0] = v.x; t[q * 16 + rr][cc + 1] = v.y;
    t[q * 16 + rr][cc + 2] = v.z; t[q * 16 + rr][cc + 3] = v.w;
  }
  __syncthreads();
  const size_t obase = (size_t)z * C * R;
#pragma unroll
  for (int q = 0; q < 4; q++) {
    const int oc = c0 + q * 16 + rr;   // output row (= input col)
    const int od = r0 + cc;            // output col base (= input row)
    ushort4 h4, l4;
    float f; u16 h;
    f = t[cc + 0][q * 16 + rr]; h = f2bf(f); h4.x = h; l4.x = f2bf(f - bf2f(h));
    f = t[cc + 1][q * 16 + rr]; h = f2bf(f); h4.y = h; l4.y = f2bf(f - bf2f(h));
    f = t[cc + 2][q * 16 + rr]; h = f2bf(f); h4.z = h; l4.z = f2bf(f - bf2f(h));
    f = t[cc + 3][q * 16 + rr]; h = f2bf(f); h4.w = h; l4.w = f2bf(f - bf2f(h));
    *(ushort4*)(oh + obase + (size_t)oc * R + od) = h4;
    *(ushort4*)(ol + obase + (size_t)oc * R + od) = l4;
  }
}

// ---------------------------------------------------------------------------
// 6) Split-bf16 MFMA GEMM: C[M,N] = A[M,K] * B[N,K]^T, A/B given as bf16
//    hi/lo planes. 128x128 tile, BK=32, 4 waves (2x2), 4x4 16x16x32 frags per
//    wave, 3 MFMA products per frag (hh + hl + lh; lo*lo dropped, ~2^-18 rel).
//    global_load_lds staging with source-side XOR slot swizzle
//    f(row)=(row>>2)&3 (rule #21: linear LDS dest, inverse-swizzled source,
//    swizzled read) so ds_read_b128 frag reads are 2-way (free, m136).
//    EPI=0: h = gelu_exact(acc + b1) -> split-store to Oh/Ol [z*CAP+m][NN]
//    EPI=1: out_e = (acc + b2) * w_slot -> Oe[(eg*CAP+m)*DOUT + n]
// ---------------------------------------------------------------------------
template<int NN, int KK, int EPI>
__global__ __launch_bounds__(256, 2) void gemm_mfma(
    const u16* __restrict__ Ah, const u16* __restrict__ Al,
    const u16* __restrict__ Bh, const u16* __restrict__ Bl,
    const float* __restrict__ bias,
    u16* __restrict__ Oh, u16* __restrict__ Ol,
    float* __restrict__ Oe, const float* __restrict__ wslot,
    int e_off)
{
  __shared__ __align__(16) u16 sAh[128 * 32], sAl[128 * 32];
  __shared__ __align__(16) u16 sBh[128 * 32], sBl[128 * 32];
  const int tid = threadIdx.x, lane = tid & 63, wid = tid >> 6;
  const int wm = wid >> 1, wn = wid & 1;
  const int m0 = blockIdx.x * 128, n0 = blockIdx.y * 128, z = blockIdx.z;
  const int eg = e_off + z;

  // wave w stages one of the 4 tiles (8 x 1KB issues each)
  u16* stile = (wid == 0) ? sAh : (wid == 1) ? sAl : (wid == 2) ? sBh : sBl;
  const u16* gsrc0;
  size_t rowbase;
  if (wid < 2) { gsrc0 = (wid == 0) ? Ah : Al; rowbase = (size_t)z * CAP + m0; }
  else         { gsrc0 = (wid == 2) ? Bh : Bl; rowbase = (size_t)z * NN  + n0; }
  const int srow_l = lane >> 2;   // row within 16-row issue group
  const int sslot  = lane & 3;    // physical 16B slot within row

  f32x4 acc[4][4] = {};

  for (int kt = 0; kt < KK; kt += 32) {
    __syncthreads();
#pragma unroll
    for (int i = 0; i < 8; i++) {
      const int row = i * 16 + srow_l;
      const int gslot = sslot ^ ((row >> 2) & 3);   // inverse swizzle on source
      const u16* src = gsrc0 + (rowbase + row) * (size_t)KK + (kt + gslot * 8);
      gload16(src, stile + i * 512);
    }
    __syncthreads();

    bf16x8 afh[4], afl[4], bfh[4], bfl[4];
#pragma unroll
    for (int mf = 0; mf < 4; mf++) {
      const int r = wm * 64 + mf * 16 + (lane & 15);
      const int off = r * 32 + (((lane >> 4) ^ ((r >> 2) & 3)) * 8);
      afh[mf] = *(const bf16x8*)(sAh + off);
      afl[mf] = *(const bf16x8*)(sAl + off);
    }
#pragma unroll
    for (int nf = 0; nf < 4; nf++) {
      const int r = wn * 64 + nf * 16 + (lane & 15);
      const int off = r * 32 + (((lane >> 4) ^ ((r >> 2) & 3)) * 8);
      bfh[nf] = *(const bf16x8*)(sBh + off);
      bfl[nf] = *(const bf16x8*)(sBl + off);
    }
#pragma unroll
    for (int mf = 0; mf < 4; mf++) {
#pragma unroll
      for (int nf = 0; nf < 4; nf++) {
        acc[mf][nf] = __builtin_amdgcn_mfma_f32_16x16x32_bf16(afh[mf], bfh[nf], acc[mf][nf], 0, 0, 0);
        acc[mf][nf] = __builtin_amdgcn_mfma_f32_16x16x32_bf16(afh[mf], bfl[nf], acc[mf][nf], 0, 0, 0);
        acc[mf][nf] = __builtin_amdgcn_mfma_f32_16x16x32_bf16(afl[mf], bfh[nf], acc[mf][nf], 0, 0, 0);
      }
    }
  }

  // epilogue: C/D layout (verified m89): col = lane&15, row = (lane>>4)*4 + r
#pragma unroll
  for (int mf = 0; mf < 4; mf++) {
#pragma unroll
    for (int nf = 0; nf < 4; nf++) {
      const int col = n0 + wn * 64 + nf * 16 + (lane & 15);
      const float bv = bias[(size_t)eg * NN + col];
#pragma unroll
      for (int r = 0; r < 4; r++) {
        const int row = m0 + wm * 64 + mf * 16 + (lane >> 4) * 4 + r;
        const float v = acc[mf][nf][r] + bv;
        if constexpr (EPI == 0) {
          const float gel = 0.5f * v * (1.0f + erff(v * 0.70710678118654752f));
          const u16 hh = f2bf(gel);
          const u16 ll = f2bf(gel - bf2f(hh));
          const size_t o = ((size_t)z * CAP + row) * NN + col;
          Oh[o] = hh; Ol[o] = ll;
        } else {
          const int slot = eg * CAP + row;
          Oe[(size_t)slot * DOUT + col] = v * wslot[slot];
        }
      }
    }
  }
}

// ---------------------------------------------------------------------------
// 7) Combine (<=2 slot rows per token, deterministic order) + LayerNorm.
// ---------------------------------------------------------------------------
__global__ __launch_bounds__(256) void combine_ln(
    const float* __restrict__ oute, const int* __restrict__ s_of_t,
    const float* __restrict__ gam, const float* __restrict__ bet,
    float* __restrict__ out)
{
  const int n = blockIdx.x, tid = threadIdx.x, lane = tid & 63, wid = tid >> 6;
  __shared__ float sred[4];
  const int s0 = s_of_t[2 * n], s1 = s_of_t[2 * n + 1];
  const int idx = tid * 4;
  float y0 = 0.f, y1 = 0.f, y2 = 0.f, y3 = 0.f;
  if (s0 >= 0) {
    const float4 a = *(const float4*)(oute + (size_t)s0 * DOUT + idx);
    y0 = a.x; y1 = a.y; y2 = a.z; y3 = a.w;
  }
  if (s1 >= 0) {
    const float4 a = *(const float4*)(oute + (size_t)s1 * DOUT + idx);
    y0 += a.x; y1 += a.y; y2 += a.z; y3 += a.w;
  }
  float ssum = y0 + y1 + y2 + y3;
  for (int o = 32; o; o >>= 1) ssum += __shfl_down(ssum, o, 64);
  if (lane == 0) sred[wid] = ssum;
  __syncthreads();
  const float mu = (sred[0] + sred[1] + sred[2] + sred[3]) * (1.f / DOUT);
  __syncthreads();
  const float d0 = y0 - mu, d1 = y1 - mu, d2 = y2 - mu, d3 = y3 - mu;
  float sq = d0 * d0 + d1 * d1 + d2 * d2 + d3 * d3;
  for (int o = 32; o; o >>= 1) sq += __shfl_down(sq, o, 64);
  if (lane == 0) sred[wid] = sq;
  __syncthreads();
  const float var = (sred[0] + sred[1] + sred[2] + sred[3]) * (1.f / DOUT);
  const float inv = 1.0f / sqrtf(var + 1e-5f);
  float4 o4;
  o4.x = d0 * inv * gam[idx + 0] + bet[idx + 0];
  o4.y = d1 * inv * gam[idx + 1] + bet[idx + 1];
  o4.z = d2 * inv * gam[idx + 2] + bet[idx + 2];
  o4.w = d3 * inv * gam[idx + 3] + bet[idx + 3];
  *(float4*)(out + (size_t)n * DOUT + idx) = o4;
}

// ---------------------------------------------------------------------------
extern "C" void kernel_launch(void* const* d_in, const int* in_sizes, int n_in,
                              void* d_out, int out_size, void* d_ws, size_t ws_size,
                              hipStream_t stream)
{
  const float* x   = (const float*)d_in[0];
  const float* rw  = (const float*)d_in[1];
  const float* rb  = (const float*)d_in[2];
  const float* w1  = (const float*)d_in[3];
  const float* b1  = (const float*)d_in[4];
  const float* w2  = (const float*)d_in[5];
  const float* b2  = (const float*)d_in[6];
  const float* lng = (const float*)d_in[7];
  const float* lnb = (const float*)d_in[8];
  float* out = (float*)d_out;

  char* base = (char*)d_ws;
  size_t off = 0;
  auto alloc = [&](size_t bytes) -> void* {
    void* p = base + off;
    off = (off + bytes + 255) & ~(size_t)255;
    return p;
  };
  int*   topi = (int*)  alloc((size_t)NTOK * TOPK * 4);
  float* topv = (float*)alloc((size_t)NTOK * TOPK * 4);
  u32*   tb   = (u32*)  alloc(NE * 4);
  int*   ntie = (int*)  alloc(NE * 4);
  int*   cnt  = (int*)  alloc(NE * 4);
  int*   tok  = (int*)  alloc((size_t)NE * CAP * 4);
  float* wsl  = (float*)alloc((size_t)NE * CAP * 4);
  int*   soft = (int*)  alloc((size_t)NTOK * TOPK * 4);
  u16*   Xh   = (u16*)  alloc((size_t)NE * CAP * DIN * 2);
  u16*   Xl   = (u16*)  alloc((size_t)NE * CAP * DIN * 2);
  float* oute = (float*)alloc((size_t)NE * CAP * DOUT * 4);
  const size_t fixed = off;

  // Per-expert group-buffer bytes: W1T(h+l) + W2T(h+l) + h(h+l)
  const size_t perE = 2 * ((size_t)DIN * HID * 2) + 2 * ((size_t)HID * DOUT * 2)
                    + 2 * ((size_t)CAP * HID * 2);
  int G = 1;
  for (int g = 8; g >= 1; g >>= 1) {
    if (fixed + (size_t)g * perE + 8192 <= ws_size) { G = g; break; }
  }
  u16* W1Th = (u16*)alloc((size_t)G * DIN * HID * 2);
  u16* W1Tl = (u16*)alloc((size_t)G * DIN * HID * 2);
  u16* W2Th = (u16*)alloc((size_t)G * HID * DOUT * 2);
  u16* W2Tl = (u16*)alloc((size_t)G * HID * DOUT * 2);
  u16* hh   = (u16*)alloc((size_t)G * CAP * HID * 2);
  u16* hl   = (u16*)alloc((size_t)G * CAP * HID * 2);

  hipMemsetAsync(cnt, 0, NE * 4, stream);
  router_topk<<<NTOK, 256, 0, stream>>>(x, rw, rb, topi, topv);
  select_caps<<<NE, 256, 0, stream>>>(topi, topv, tb, ntie);
  assign_slots<<<NTOK * TOPK / 256, 256, 0, stream>>>(topi, topv, tb, ntie, cnt, tok, wsl, soft);
  gather_x<<<NE * CAP, 256, 0, stream>>>(x, tok, cnt, Xh, Xl);

  for (int g0 = 0; g0 < NE; g0 += G) {
    transpose_split<<<dim3(HID / 64, DIN / 64, G), 256, 0, stream>>>(w1, W1Th, W1Tl, DIN, HID, g0);
    transpose_split<<<dim3(DOUT / 64, HID / 64, G), 256, 0, stream>>>(w2, W2Th, W2Tl, HID, DOUT, g0);
    gemm_mfma<HID, DIN, 0><<<dim3(CAP / 128, HID / 128, G), 256, 0, stream>>>(
        Xh + (size_t)g0 * CAP * DIN, Xl + (size_t)g0 * CAP * DIN,
        W1Th, W1Tl, b1, hh, hl, nullptr, nullptr, g0);
    gemm_mfma<DOUT, HID, 1><<<dim3(CAP / 128, DOUT / 128, G), 256, 0, stream>>>(
        hh, hl, W2Th, W2Tl, b2, nullptr, nullptr, oute, wsl, g0);
  }

  combine_ln<<<NTOK, 256, 0, stream>>>(oute, soft, lng, lnb, out);
}

// Round 3
// 1349.651 us; speedup vs baseline: 1.8684x; 1.8684x over previous
//
#include <hip/hip_runtime.h>

// ============================================================================
// MoE SparseDispatcher (B=4,S=2048,D=1024,H=4096,DO=1024,E=8,K=2,cap=1536)
// Round 3: fix assign_slots (was 1335us = 53% of total: the tie-rank backward
// scan is a latency chain that ALWAYS runs for the threshold entry). Replaced
// with per-expert ordered ballot-prefix scan (no atomics, ~15us). Everything
// else identical to Round 2 (passed, absmax 0.0156).
// ============================================================================

typedef unsigned short u16;
typedef unsigned int   u32;
typedef short bf16x8 __attribute__((ext_vector_type(8)));   // 8 bf16 bit patterns
typedef float f32x4  __attribute__((ext_vector_type(4)));

constexpr int NTOK = 4 * 2048;   // 8192 tokens
constexpr int DIN  = 1024;
constexpr int HID  = 4096;
constexpr int DOUT = 1024;
constexpr int NE   = 8;
constexpr int TOPK = 2;
constexpr int CAP  = 1536;       // max(int(8192*1.5/8), 2)

__device__ __forceinline__ u16 f2bf(float f) {          // round-to-nearest-even
  u32 u = __float_as_uint(f);
  u32 r = u + 0x7FFFu + ((u >> 16) & 1u);
  return (u16)(r >> 16);
}
__device__ __forceinline__ float bf2f(u16 h) {
  return __uint_as_float(((u32)h) << 16);
}
__device__ __forceinline__ void gload16(const u16* g, u16* l) {
  __builtin_amdgcn_global_load_lds(
      (const __attribute__((address_space(1))) void*)g,
      (__attribute__((address_space(3))) void*)l, 16, 0, 0);
}

// ---------------------------------------------------------------------------
// 1) Router: logits = x@rw + rb; softmax; top-2 (ties -> lower index, matches
//    lax.top_k); renormalized weights. One block per token.
// ---------------------------------------------------------------------------
__global__ __launch_bounds__(256) void router_topk(
    const float* __restrict__ x, const float* __restrict__ rw,
    const float* __restrict__ rb, int* __restrict__ topi, float* __restrict__ topv)
{
  const int n = blockIdx.x, tid = threadIdx.x, lane = tid & 63, wid = tid >> 6;
  float p[NE] = {0.f,0.f,0.f,0.f,0.f,0.f,0.f,0.f};
  const float* xr = x + (size_t)n * DIN;
  for (int d = tid; d < DIN; d += 256) {
    float xv = xr[d];
    const float* rwd = rw + d * NE;
#pragma unroll
    for (int e = 0; e < NE; e++) p[e] += xv * rwd[e];
  }
#pragma unroll
  for (int e = 0; e < NE; e++)
    for (int o = 32; o; o >>= 1) p[e] += __shfl_down(p[e], o, 64);
  __shared__ float red[4][NE];
  if (lane == 0) {
#pragma unroll
    for (int e = 0; e < NE; e++) red[wid][e] = p[e];
  }
  __syncthreads();
  if (tid == 0) {
    float l[NE], mx = -1e30f;
#pragma unroll
    for (int e = 0; e < NE; e++) {
      l[e] = red[0][e] + red[1][e] + red[2][e] + red[3][e] + rb[e];
      mx = fmaxf(mx, l[e]);
    }
    float s = 0.f, pr[NE];
#pragma unroll
    for (int e = 0; e < NE; e++) { pr[e] = expf(l[e] - mx); s += pr[e]; }
#pragma unroll
    for (int e = 0; e < NE; e++) pr[e] /= s;
    int i0 = 0; float v0 = pr[0];
    for (int e = 1; e < NE; e++) if (pr[e] > v0) { v0 = pr[e]; i0 = e; }
    int i1 = -1; float v1 = -1.f;
    for (int e = 0; e < NE; e++) if (e != i0 && pr[e] > v1) { v1 = pr[e]; i1 = e; }
    float sum = v0 + v1;
    topi[2*n] = i0; topi[2*n+1] = i1;
    topv[2*n] = v0 / sum; topv[2*n+1] = v1 / sum;
  }
}

// ---------------------------------------------------------------------------
// 2) Exact per-expert capacity threshold: radix-select (MSB->LSB, 4 bytes) on
//    positive-float bit patterns (order-isomorphic to float order). Outputs
//    the CAP-th largest value's bits and how many tied-at-threshold entries
//    to keep (ties -> ascending flat index, matching lax.top_k).
//    keep-all case: t_bits=0, ntie=0 (all v>0 pass).
// ---------------------------------------------------------------------------
__global__ void select_caps(const int* __restrict__ topi, const float* __restrict__ topv,
                            u32* __restrict__ t_bits, int* __restrict__ ntie)
{
  const int e = blockIdx.x, tid = threadIdx.x;
  __shared__ u32 hist[256];
  __shared__ u32 s_prefix;
  __shared__ int s_rank, s_done;
  if (tid == 0) { s_prefix = 0u; s_rank = CAP; s_done = 0; }
  __syncthreads();
  for (int byte = 3; byte >= 0; --byte) {
    hist[tid] = 0u;
    __syncthreads();
    const u32 pfx = s_prefix;
    const u32 him = (byte == 3) ? 0u : (0xFFFFFFFFu << ((byte + 1) * 8));
    for (int f = tid; f < NTOK * TOPK; f += 256) {
      if (topi[f] == e) {
        u32 u = __float_as_uint(topv[f]);
        if ((u & him) == pfx) atomicAdd(&hist[(u >> (byte * 8)) & 255u], 1u);
      }
    }
    __syncthreads();
    if (tid == 0) {
      if (byte == 3) {
        int total = 0;
        for (int b = 0; b < 256; b++) total += (int)hist[b];
        if (total <= CAP) { t_bits[e] = 0u; ntie[e] = 0; s_done = 1; }
      }
      if (!s_done) {
        int R = s_rank, cum = 0, b;
        for (b = 255; b >= 0; --b) { cum += (int)hist[b]; if (cum >= R) break; }
        s_prefix = s_prefix | (((u32)b) << (byte * 8));
        s_rank = R - (cum - (int)hist[b]);
      }
    }
    __syncthreads();
    if (s_done) return;
  }
  if (tid == 0) { t_bits[e] = s_prefix; ntie[e] = s_rank; }
}

// ---------------------------------------------------------------------------
// 3) Assign kept (token,k) pairs to expert slots. One block per expert scans
//    the flat [NTOK*TOPK] array IN ORDER; ballot+popcount wave prefix + LDS
//    cross-wave prefix gives (a) tie rank among vb==t entries (ascending flat
//    index, matching lax.top_k) and (b) the slot index. No atomics, no
//    latency chains. Writes s_of_t[f] (slot or -1) for every owned f, and
//    final cnt[e].
// ---------------------------------------------------------------------------
__global__ __launch_bounds__(256) void assign_slots(
    const int* __restrict__ topi, const float* __restrict__ topv,
    const u32* __restrict__ tb, const int* __restrict__ ntie,
    int* __restrict__ cnt, int* __restrict__ tok,
    float* __restrict__ wsl, int* __restrict__ s_of_t)
{
  const int e = blockIdx.x;
  const int tid = threadIdx.x, lane = tid & 63, wid = tid >> 6;
  const u32 t = tb[e];
  const int nt = ntie[e];
  __shared__ int wtie[4], wkeep[4];
  int run_tie = 0, run_keep = 0;
  const unsigned long long lanemask = (lane == 63) ? ~0ull >> 1 : ((1ull << (lane + 1)) - 1ull) >> 1;
  // lanemask = bits below `lane`
  for (int base = 0; base < NTOK * TOPK; base += 256) {
    const int f = base + tid;
    const bool mine = (topi[f] == e);
    const float v = topv[f];
    const u32 vb = __float_as_uint(v);
    const bool tied  = mine && (vb == t);
    const bool keep0 = mine && (vb > t);
    const unsigned long long mt = __ballot(tied);
    const int tie_pre = __popcll(mt & lanemask);
    if (lane == 0) wtie[wid] = __popcll(mt);
    __syncthreads();
    int tie_base = run_tie;
    for (int w = 0; w < wid; w++) tie_base += wtie[w];
    const bool keep = keep0 || (tied && (tie_base + tie_pre) < nt);
    const unsigned long long mk = __ballot(keep);
    const int keep_pre = __popcll(mk & lanemask);
    if (lane == 0) wkeep[wid] = __popcll(mk);
    __syncthreads();
    int keep_base = run_keep;
    for (int w = 0; w < wid; w++) keep_base += wkeep[w];
    if (mine) {
      int sl = -1;
      if (keep) {
        sl = e * CAP + keep_base + keep_pre;
        tok[sl] = f >> 1;
        wsl[sl] = v;
      }
      s_of_t[f] = sl;
    }
    run_tie  += wtie[0]  + wtie[1]  + wtie[2]  + wtie[3];
    run_keep += wkeep[0] + wkeep[1] + wkeep[2] + wkeep[3];
    __syncthreads();   // wtie/wkeep reused next iteration
  }
  if (tid == 0) cnt[e] = run_keep;
}

// ---------------------------------------------------------------------------
// 4) Gather token rows -> Xe bf16 hi/lo planes [E*CAP][DIN]; pad rows zeroed.
// ---------------------------------------------------------------------------
__global__ __launch_bounds__(256) void gather_x(
    const float* __restrict__ x, const int* __restrict__ tok, const int* __restrict__ cnt,
    u16* __restrict__ Xh, u16* __restrict__ Xl)
{
  const int slot = blockIdx.x;
  const int e = slot / CAP, c = slot % CAP;
  const int tid = threadIdx.x;
  const size_t ob = (size_t)slot * DIN + tid * 4;
  ushort4 h4, l4;
  if (c < cnt[e]) {
    const int n = tok[slot];
    const float4 v = *(const float4*)(x + (size_t)n * DIN + tid * 4);
    u16 h, l;
    h = f2bf(v.x); l = f2bf(v.x - bf2f(h)); h4.x = h; l4.x = l;
    h = f2bf(v.y); l = f2bf(v.y - bf2f(h)); h4.y = h; l4.y = l;
    h = f2bf(v.z); l = f2bf(v.z - bf2f(h)); h4.z = h; l4.z = l;
    h = f2bf(v.w); l = f2bf(v.w - bf2f(h)); h4.w = h; l4.w = l;
  } else {
    h4.x = h4.y = h4.z = h4.w = 0; l4 = h4;
  }
  *(ushort4*)(Xh + ob) = h4;
  *(ushort4*)(Xl + ob) = l4;
}

// ---------------------------------------------------------------------------
// 5) Transpose+split weights: in [E][R][C] fp32 (expert e_off+z) -> out
//    [z][C][R] bf16 hi/lo. 64x64 tiles via LDS (stride 65: conflict-free).
// ---------------------------------------------------------------------------
__global__ __launch_bounds__(256) void transpose_split(
    const float* __restrict__ in, u16* __restrict__ oh, u16* __restrict__ ol,
    int R, int C, int e_off)
{
  const int z = blockIdx.z, e = e_off + z;
  const int c0 = blockIdx.x * 64, r0 = blockIdx.y * 64;
  const int tid = threadIdx.x;
  const int rr = tid >> 4;          // 0..15
  const int cc = (tid & 15) * 4;    // 0..60
  __shared__ float t[64][65];
  const float* ibase = in + (size_t)e * R * C;
#pragma unroll
  for (int q = 0; q < 4; q++) {
    const float4 v = *(const float4*)(ibase + (size_t)(r0 + q * 16 + rr) * C + c0 + cc);
    t[q * 16 + rr][cc + 0] = v.x; t[q * 16 + rr][cc + 1] = v.y;
    t[q * 16 + rr][cc + 2] = v.z; t[q * 16 + rr][cc + 3] = v.w;
  }
  __syncthreads();
  const size_t obase = (size_t)z * C * R;
#pragma unroll
  for (int q = 0; q < 4; q++) {
    const int oc = c0 + q * 16 + rr;   // output row (= input col)
    const int od = r0 + cc;            // output col base (= input row)
    ushort4 h4, l4;
    float f; u16 h;
    f = t[cc + 0][q * 16 + rr]; h = f2bf(f); h4.x = h; l4.x = f2bf(f - bf2f(h));
    f = t[cc + 1][q * 16 + rr]; h = f2bf(f); h4.y = h; l4.y = f2bf(f - bf2f(h));
    f = t[cc + 2][q * 16 + rr]; h = f2bf(f); h4.z = h; l4.z = f2bf(f - bf2f(h));
    f = t[cc + 3][q * 16 + rr]; h = f2bf(f); h4.w = h; l4.w = f2bf(f - bf2f(h));
    *(ushort4*)(oh + obase + (size_t)oc * R + od) = h4;
    *(ushort4*)(ol + obase + (size_t)oc * R + od) = l4;
  }
}

// ---------------------------------------------------------------------------
// 6) Split-bf16 MFMA GEMM: C[M,N] = A[M,K] * B[N,K]^T, A/B given as bf16
//    hi/lo planes. 128x128 tile, BK=32, 4 waves (2x2), 4x4 16x16x32 frags per
//    wave, 3 MFMA products per frag (hh + hl + lh; lo*lo dropped, ~2^-18 rel).
//    global_load_lds staging with source-side XOR slot swizzle
//    f(row)=(row>>2)&3 (rule #21: linear LDS dest, inverse-swizzled source,
//    swizzled read) so ds_read_b128 frag reads are 2-way (free, m136).
//    EPI=0: h = gelu_exact(acc + b1) -> split-store to Oh/Ol [z*CAP+m][NN]
//    EPI=1: out_e = (acc + b2) * w_slot -> Oe[(eg*CAP+m)*DOUT + n]
// ---------------------------------------------------------------------------
template<int NN, int KK, int EPI>
__global__ __launch_bounds__(256, 2) void gemm_mfma(
    const u16* __restrict__ Ah, const u16* __restrict__ Al,
    const u16* __restrict__ Bh, const u16* __restrict__ Bl,
    const float* __restrict__ bias,
    u16* __restrict__ Oh, u16* __restrict__ Ol,
    float* __restrict__ Oe, const float* __restrict__ wslot,
    int e_off)
{
  __shared__ __align__(16) u16 sAh[128 * 32], sAl[128 * 32];
  __shared__ __align__(16) u16 sBh[128 * 32], sBl[128 * 32];
  const int tid = threadIdx.x, lane = tid & 63, wid = tid >> 6;
  const int wm = wid >> 1, wn = wid & 1;
  const int m0 = blockIdx.x * 128, n0 = blockIdx.y * 128, z = blockIdx.z;
  const int eg = e_off + z;

  // wave w stages one of the 4 tiles (8 x 1KB issues each)
  u16* stile = (wid == 0) ? sAh : (wid == 1) ? sAl : (wid == 2) ? sBh : sBl;
  const u16* gsrc0;
  size_t rowbase;
  if (wid < 2) { gsrc0 = (wid == 0) ? Ah : Al; rowbase = (size_t)z * CAP + m0; }
  else         { gsrc0 = (wid == 2) ? Bh : Bl; rowbase = (size_t)z * NN  + n0; }
  const int srow_l = lane >> 2;   // row within 16-row issue group
  const int sslot  = lane & 3;    // physical 16B slot within row

  f32x4 acc[4][4] = {};

  for (int kt = 0; kt < KK; kt += 32) {
    __syncthreads();
#pragma unroll
    for (int i = 0; i < 8; i++) {
      const int row = i * 16 + srow_l;
      const int gslot = sslot ^ ((row >> 2) & 3);   // inverse swizzle on source
      const u16* src = gsrc0 + (rowbase + row) * (size_t)KK + (kt + gslot * 8);
      gload16(src, stile + i * 512);
    }
    __syncthreads();

    bf16x8 afh[4], afl[4], bfh[4], bfl[4];
#pragma unroll
    for (int mf = 0; mf < 4; mf++) {
      const int r = wm * 64 + mf * 16 + (lane & 15);
      const int off = r * 32 + (((lane >> 4) ^ ((r >> 2) & 3)) * 8);
      afh[mf] = *(const bf16x8*)(sAh + off);
      afl[mf] = *(const bf16x8*)(sAl + off);
    }
#pragma unroll
    for (int nf = 0; nf < 4; nf++) {
      const int r = wn * 64 + nf * 16 + (lane & 15);
      const int off = r * 32 + (((lane >> 4) ^ ((r >> 2) & 3)) * 8);
      bfh[nf] = *(const bf16x8*)(sBh + off);
      bfl[nf] = *(const bf16x8*)(sBl + off);
    }
#pragma unroll
    for (int mf = 0; mf < 4; mf++) {
#pragma unroll
      for (int nf = 0; nf < 4; nf++) {
        acc[mf][nf] = __builtin_amdgcn_mfma_f32_16x16x32_bf16(afh[mf], bfh[nf], acc[mf][nf], 0, 0, 0);
        acc[mf][nf] = __builtin_amdgcn_mfma_f32_16x16x32_bf16(afh[mf], bfl[nf], acc[mf][nf], 0, 0, 0);
        acc[mf][nf] = __builtin_amdgcn_mfma_f32_16x16x32_bf16(afl[mf], bfh[nf], acc[mf][nf], 0, 0, 0);
      }
    }
  }

  // epilogue: C/D layout (verified m89): col = lane&15, row = (lane>>4)*4 + r
#pragma unroll
  for (int mf = 0; mf < 4; mf++) {
#pragma unroll
    for (int nf = 0; nf < 4; nf++) {
      const int col = n0 + wn * 64 + nf * 16 + (lane & 15);
      const float bv = bias[(size_t)eg * NN + col];
#pragma unroll
      for (int r = 0; r < 4; r++) {
        const int row = m0 + wm * 64 + mf * 16 + (lane >> 4) * 4 + r;
        const float v = acc[mf][nf][r] + bv;
        if constexpr (EPI == 0) {
          const float gel = 0.5f * v * (1.0f + erff(v * 0.70710678118654752f));
          const u16 hh = f2bf(gel);
          const u16 ll = f2bf(gel - bf2f(hh));
          const size_t o = ((size_t)z * CAP + row) * NN + col;
          Oh[o] = hh; Ol[o] = ll;
        } else {
          const int slot = eg * CAP + row;
          Oe[(size_t)slot * DOUT + col] = v * wslot[slot];
        }
      }
    }
  }
}

// ---------------------------------------------------------------------------
// 7) Combine (<=2 slot rows per token, deterministic order) + LayerNorm.
// ---------------------------------------------------------------------------
__global__ __launch_bounds__(256) void combine_ln(
    const float* __restrict__ oute, const int* __restrict__ s_of_t,
    const float* __restrict__ gam, const float* __restrict__ bet,
    float* __restrict__ out)
{
  const int n = blockIdx.x, tid = threadIdx.x, lane = tid & 63, wid = tid >> 6;
  __shared__ float sred[4];
  const int s0 = s_of_t[2 * n], s1 = s_of_t[2 * n + 1];
  const int idx = tid * 4;
  float y0 = 0.f, y1 = 0.f, y2 = 0.f, y3 = 0.f;
  if (s0 >= 0) {
    const float4 a = *(const float4*)(oute + (size_t)s0 * DOUT + idx);
    y0 = a.x; y1 = a.y; y2 = a.z; y3 = a.w;
  }
  if (s1 >= 0) {
    const float4 a = *(const float4*)(oute + (size_t)s1 * DOUT + idx);
    y0 += a.x; y1 += a.y; y2 += a.z; y3 += a.w;
  }
  float ssum = y0 + y1 + y2 + y3;
  for (int o = 32; o; o >>= 1) ssum += __shfl_down(ssum, o, 64);
  if (lane == 0) sred[wid] = ssum;
  __syncthreads();
  const float mu = (sred[0] + sred[1] + sred[2] + sred[3]) * (1.f / DOUT);
  __syncthreads();
  const float d0 = y0 - mu, d1 = y1 - mu, d2 = y2 - mu, d3 = y3 - mu;
  float sq = d0 * d0 + d1 * d1 + d2 * d2 + d3 * d3;
  for (int o = 32; o; o >>= 1) sq += __shfl_down(sq, o, 64);
  if (lane == 0) sred[wid] = sq;
  __syncthreads();
  const float var = (sred[0] + sred[1] + sred[2] + sred[3]) * (1.f / DOUT);
  const float inv = 1.0f / sqrtf(var + 1e-5f);
  float4 o4;
  o4.x = d0 * inv * gam[idx + 0] + bet[idx + 0];
  o4.y = d1 * inv * gam[idx + 1] + bet[idx + 1];
  o4.z = d2 * inv * gam[idx + 2] + bet[idx + 2];
  o4.w = d3 * inv * gam[idx + 3] + bet[idx + 3];
  *(float4*)(out + (size_t)n * DOUT + idx) = o4;
}

// ---------------------------------------------------------------------------
extern "C" void kernel_launch(void* const* d_in, const int* in_sizes, int n_in,
                              void* d_out, int out_size, void* d_ws, size_t ws_size,
                              hipStream_t stream)
{
  const float* x   = (const float*)d_in[0];
  const float* rw  = (const float*)d_in[1];
  const float* rb  = (const float*)d_in[2];
  const float* w1  = (const float*)d_in[3];
  const float* b1  = (const float*)d_in[4];
  const float* w2  = (const float*)d_in[5];
  const float* b2  = (const float*)d_in[6];
  const float* lng = (const float*)d_in[7];
  const float* lnb = (const float*)d_in[8];
  float* out = (float*)d_out;

  char* base = (char*)d_ws;
  size_t off = 0;
  auto alloc = [&](size_t bytes) -> void* {
    void* p = base + off;
    off = (off + bytes + 255) & ~(size_t)255;
    return p;
  };
  int*   topi = (int*)  alloc((size_t)NTOK * TOPK * 4);
  float* topv = (float*)alloc((size_t)NTOK * TOPK * 4);
  u32*   tb   = (u32*)  alloc(NE * 4);
  int*   ntie = (int*)  alloc(NE * 4);
  int*   cnt  = (int*)  alloc(NE * 4);
  int*   tok  = (int*)  alloc((size_t)NE * CAP * 4);
  float* wsl  = (float*)alloc((size_t)NE * CAP * 4);
  int*   soft = (int*)  alloc((size_t)NTOK * TOPK * 4);
  u16*   Xh   = (u16*)  alloc((size_t)NE * CAP * DIN * 2);
  u16*   Xl   = (u16*)  alloc((size_t)NE * CAP * DIN * 2);
  float* oute = (float*)alloc((size_t)NE * CAP * DOUT * 4);
  const size_t fixed = off;

  // Per-expert group-buffer bytes: W1T(h+l) + W2T(h+l) + h(h+l)
  const size_t perE = 2 * ((size_t)DIN * HID * 2) + 2 * ((size_t)HID * DOUT * 2)
                    + 2 * ((size_t)CAP * HID * 2);
  int G = 1;
  for (int g = 8; g >= 1; g >>= 1) {
    if (fixed + (size_t)g * perE + 8192 <= ws_size) { G = g; break; }
  }
  u16* W1Th = (u16*)alloc((size_t)G * DIN * HID * 2);
  u16* W1Tl = (u16*)alloc((size_t)G * DIN * HID * 2);
  u16* W2Th = (u16*)alloc((size_t)G * HID * DOUT * 2);
  u16* W2Tl = (u16*)alloc((size_t)G * HID * DOUT * 2);
  u16* hh   = (u16*)alloc((size_t)G * CAP * HID * 2);
  u16* hl   = (u16*)alloc((size_t)G * CAP * HID * 2);

  router_topk<<<NTOK, 256, 0, stream>>>(x, rw, rb, topi, topv);
  select_caps<<<NE, 256, 0, stream>>>(topi, topv, tb, ntie);
  assign_slots<<<NE, 256, 0, stream>>>(topi, topv, tb, ntie, cnt, tok, wsl, soft);
  gather_x<<<NE * CAP, 256, 0, stream>>>(x, tok, cnt, Xh, Xl);

  for (int g0 = 0; g0 < NE; g0 += G) {
    transpose_split<<<dim3(HID / 64, DIN / 64, G), 256, 0, stream>>>(w1, W1Th, W1Tl, DIN, HID, g0);
    transpose_split<<<dim3(DOUT / 64, HID / 64, G), 256, 0, stream>>>(w2, W2Th, W2Tl, HID, DOUT, g0);
    gemm_mfma<HID, DIN, 0><<<dim3(CAP / 128, HID / 128, G), 256, 0, stream>>>(
        Xh + (size_t)g0 * CAP * DIN, Xl + (size_t)g0 * CAP * DIN,
        W1Th, W1Tl, b1, hh, hl, nullptr, nullptr, g0);
    gemm_mfma<DOUT, HID, 1><<<dim3(CAP / 128, DOUT / 128, G), 256, 0, stream>>>(
        hh, hl, W2Th, W2Tl, b2, nullptr, nullptr, oute, wsl, g0);
  }

  combine_ln<<<NTOK, 256, 0, stream>>>(oute, soft, lng, lnb, out);
}

// Round 4
// 1262.813 us; speedup vs baseline: 1.9969x; 1.0688x over previous
//
#include <hip/hip_runtime.h>

// ============================================================================
// MoE SparseDispatcher (B=4,S=2048,D=1024,H=4096,DO=1024,E=8,K=2,cap=1536)
// Round 4: GEMM rewrite. R3 post-mortem: gemm_mfma at MfmaUtil 25.5%, 2
// vmcnt(0)-draining barriers per 32-K step (stall-bound), FETCH 356MB
// (XCD L2 thrash), WRITE 137MB (2B-store RFO), GEMM2 grid 192 blocks.
// Changes: (1) double-buffered LDS + depth-2 prefetch + raw s_barrier +
// counted vmcnt(8) (no drain) + setprio; (2) bijective XCD chunk swizzle;
// (3) GEMM1 epilogue LDS-bounce -> ushort4 stores; (4) GEMM2 K-split x4
// with fp32 atomicAdd into zeroed oute (grid 768). Numerics unchanged
// (bf16 hi/lo 3-product split = fp32 quality).
// ============================================================================

typedef unsigned short u16;
typedef unsigned int   u32;
typedef short bf16x8 __attribute__((ext_vector_type(8)));   // 8 bf16 bit patterns
typedef float f32x4  __attribute__((ext_vector_type(4)));

constexpr int NTOK = 4 * 2048;   // 8192 tokens
constexpr int DIN  = 1024;
constexpr int HID  = 4096;
constexpr int DOUT = 1024;
constexpr int NE   = 8;
constexpr int TOPK = 2;
constexpr int CAP  = 1536;       // max(int(8192*1.5/8), 2)

__device__ __forceinline__ u16 f2bf(float f) {          // round-to-nearest-even
  u32 u = __float_as_uint(f);
  u32 r = u + 0x7FFFu + ((u >> 16) & 1u);
  return (u16)(r >> 16);
}
__device__ __forceinline__ float bf2f(u16 h) {
  return __uint_as_float(((u32)h) << 16);
}
__device__ __forceinline__ void gload16(const u16* g, u16* l) {
  __builtin_amdgcn_global_load_lds(
      (const __attribute__((address_space(1))) void*)g,
      (__attribute__((address_space(3))) void*)l, 16, 0, 0);
}

// ---------------------------------------------------------------------------
// 1) Router: logits = x@rw + rb; softmax; top-2; renormalized weights.
// ---------------------------------------------------------------------------
__global__ __launch_bounds__(256) void router_topk(
    const float* __restrict__ x, const float* __restrict__ rw,
    const float* __restrict__ rb, int* __restrict__ topi, float* __restrict__ topv)
{
  const int n = blockIdx.x, tid = threadIdx.x, lane = tid & 63, wid = tid >> 6;
  float p[NE] = {0.f,0.f,0.f,0.f,0.f,0.f,0.f,0.f};
  const float* xr = x + (size_t)n * DIN;
  for (int d = tid; d < DIN; d += 256) {
    float xv = xr[d];
    const float* rwd = rw + d * NE;
#pragma unroll
    for (int e = 0; e < NE; e++) p[e] += xv * rwd[e];
  }
#pragma unroll
  for (int e = 0; e < NE; e++)
    for (int o = 32; o; o >>= 1) p[e] += __shfl_down(p[e], o, 64);
  __shared__ float red[4][NE];
  if (lane == 0) {
#pragma unroll
    for (int e = 0; e < NE; e++) red[wid][e] = p[e];
  }
  __syncthreads();
  if (tid == 0) {
    float l[NE], mx = -1e30f;
#pragma unroll
    for (int e = 0; e < NE; e++) {
      l[e] = red[0][e] + red[1][e] + red[2][e] + red[3][e] + rb[e];
      mx = fmaxf(mx, l[e]);
    }
    float s = 0.f, pr[NE];
#pragma unroll
    for (int e = 0; e < NE; e++) { pr[e] = expf(l[e] - mx); s += pr[e]; }
#pragma unroll
    for (int e = 0; e < NE; e++) pr[e] /= s;
    int i0 = 0; float v0 = pr[0];
    for (int e = 1; e < NE; e++) if (pr[e] > v0) { v0 = pr[e]; i0 = e; }
    int i1 = -1; float v1 = -1.f;
    for (int e = 0; e < NE; e++) if (e != i0 && pr[e] > v1) { v1 = pr[e]; i1 = e; }
    float sum = v0 + v1;
    topi[2*n] = i0; topi[2*n+1] = i1;
    topv[2*n] = v0 / sum; topv[2*n+1] = v1 / sum;
  }
}

// ---------------------------------------------------------------------------
// 2) Exact per-expert capacity threshold: 4-pass radix-select on positive-
//    float bit patterns. Ties -> ascending flat index (lax.top_k semantics).
// ---------------------------------------------------------------------------
__global__ void select_caps(const int* __restrict__ topi, const float* __restrict__ topv,
                            u32* __restrict__ t_bits, int* __restrict__ ntie)
{
  const int e = blockIdx.x, tid = threadIdx.x;
  __shared__ u32 hist[256];
  __shared__ u32 s_prefix;
  __shared__ int s_rank, s_done;
  if (tid == 0) { s_prefix = 0u; s_rank = CAP; s_done = 0; }
  __syncthreads();
  for (int byte = 3; byte >= 0; --byte) {
    hist[tid] = 0u;
    __syncthreads();
    const u32 pfx = s_prefix;
    const u32 him = (byte == 3) ? 0u : (0xFFFFFFFFu << ((byte + 1) * 8));
    for (int f = tid; f < NTOK * TOPK; f += 256) {
      if (topi[f] == e) {
        u32 u = __float_as_uint(topv[f]);
        if ((u & him) == pfx) atomicAdd(&hist[(u >> (byte * 8)) & 255u], 1u);
      }
    }
    __syncthreads();
    if (tid == 0) {
      if (byte == 3) {
        int total = 0;
        for (int b = 0; b < 256; b++) total += (int)hist[b];
        if (total <= CAP) { t_bits[e] = 0u; ntie[e] = 0; s_done = 1; }
      }
      if (!s_done) {
        int R = s_rank, cum = 0, b;
        for (b = 255; b >= 0; --b) { cum += (int)hist[b]; if (cum >= R) break; }
        s_prefix = s_prefix | (((u32)b) << (byte * 8));
        s_rank = R - (cum - (int)hist[b]);
      }
    }
    __syncthreads();
    if (s_done) return;
  }
  if (tid == 0) { t_bits[e] = s_prefix; ntie[e] = s_rank; }
}

// ---------------------------------------------------------------------------
// 3) Assign kept (token,k) pairs to expert slots: per-expert ordered
//    ballot-prefix scan (R3 fix; no atomics, no latency chains).
// ---------------------------------------------------------------------------
__global__ __launch_bounds__(256) void assign_slots(
    const int* __restrict__ topi, const float* __restrict__ topv,
    const u32* __restrict__ tb, const int* __restrict__ ntie,
    int* __restrict__ cnt, int* __restrict__ tok,
    float* __restrict__ wsl, int* __restrict__ s_of_t)
{
  const int e = blockIdx.x;
  const int tid = threadIdx.x, lane = tid & 63, wid = tid >> 6;
  const u32 t = tb[e];
  const int nt = ntie[e];
  __shared__ int wtie[4], wkeep[4];
  int run_tie = 0, run_keep = 0;
  const unsigned long long lanemask = (lane == 63) ? ~0ull >> 1 : ((1ull << (lane + 1)) - 1ull) >> 1;
  for (int base = 0; base < NTOK * TOPK; base += 256) {
    const int f = base + tid;
    const bool mine = (topi[f] == e);
    const float v = topv[f];
    const u32 vb = __float_as_uint(v);
    const bool tied  = mine && (vb == t);
    const bool keep0 = mine && (vb > t);
    const unsigned long long mt = __ballot(tied);
    const int tie_pre = __popcll(mt & lanemask);
    if (lane == 0) wtie[wid] = __popcll(mt);
    __syncthreads();
    int tie_base = run_tie;
    for (int w = 0; w < wid; w++) tie_base += wtie[w];
    const bool keep = keep0 || (tied && (tie_base + tie_pre) < nt);
    const unsigned long long mk = __ballot(keep);
    const int keep_pre = __popcll(mk & lanemask);
    if (lane == 0) wkeep[wid] = __popcll(mk);
    __syncthreads();
    int keep_base = run_keep;
    for (int w = 0; w < wid; w++) keep_base += wkeep[w];
    if (mine) {
      int sl = -1;
      if (keep) {
        sl = e * CAP + keep_base + keep_pre;
        tok[sl] = f >> 1;
        wsl[sl] = v;
      }
      s_of_t[f] = sl;
    }
    run_tie  += wtie[0]  + wtie[1]  + wtie[2]  + wtie[3];
    run_keep += wkeep[0] + wkeep[1] + wkeep[2] + wkeep[3];
    __syncthreads();
  }
  if (tid == 0) cnt[e] = run_keep;
}

// ---------------------------------------------------------------------------
// 4) Gather token rows -> Xe bf16 hi/lo planes [E*CAP][DIN]; pad rows zeroed.
// ---------------------------------------------------------------------------
__global__ __launch_bounds__(256) void gather_x(
    const float* __restrict__ x, const int* __restrict__ tok, const int* __restrict__ cnt,
    u16* __restrict__ Xh, u16* __restrict__ Xl)
{
  const int slot = blockIdx.x;
  const int e = slot / CAP, c = slot % CAP;
  const int tid = threadIdx.x;
  const size_t ob = (size_t)slot * DIN + tid * 4;
  ushort4 h4, l4;
  if (c < cnt[e]) {
    const int n = tok[slot];
    const float4 v = *(const float4*)(x + (size_t)n * DIN + tid * 4);
    u16 h, l;
    h = f2bf(v.x); l = f2bf(v.x - bf2f(h)); h4.x = h; l4.x = l;
    h = f2bf(v.y); l = f2bf(v.y - bf2f(h)); h4.y = h; l4.y = l;
    h = f2bf(v.z); l = f2bf(v.z - bf2f(h)); h4.z = h; l4.z = l;
    h = f2bf(v.w); l = f2bf(v.w - bf2f(h)); h4.w = h; l4.w = l;
  } else {
    h4.x = h4.y = h4.z = h4.w = 0; l4 = h4;
  }
  *(ushort4*)(Xh + ob) = h4;
  *(ushort4*)(Xl + ob) = l4;
}

// ---------------------------------------------------------------------------
// 5) Transpose+split weights: in [E][R][C] fp32 -> out [z][C][R] bf16 hi/lo.
// ---------------------------------------------------------------------------
__global__ __launch_bounds__(256) void transpose_split(
    const float* __restrict__ in, u16* __restrict__ oh, u16* __restrict__ ol,
    int R, int C, int e_off)
{
  const int z = blockIdx.z, e = e_off + z;
  const int c0 = blockIdx.x * 64, r0 = blockIdx.y * 64;
  const int tid = threadIdx.x;
  const int rr = tid >> 4;
  const int cc = (tid & 15) * 4;
  __shared__ float t[64][65];
  const float* ibase = in + (size_t)e * R * C;
#pragma unroll
  for (int q = 0; q < 4; q++) {
    const float4 v = *(const float4*)(ibase + (size_t)(r0 + q * 16 + rr) * C + c0 + cc);
    t[q * 16 + rr][cc + 0] = v.x; t[q * 16 + rr][cc + 1] = v.y;
    t[q * 16 + rr][cc + 2] = v.z; t[q * 16 + rr][cc + 3] = v.w;
  }
  __syncthreads();
  const size_t obase = (size_t)z * C * R;
#pragma unroll
  for (int q = 0; q < 4; q++) {
    const int oc = c0 + q * 16 + rr;
    const int od = r0 + cc;
    ushort4 h4, l4;
    float f; u16 h;
    f = t[cc + 0][q * 16 + rr]; h = f2bf(f); h4.x = h; l4.x = f2bf(f - bf2f(h));
    f = t[cc + 1][q * 16 + rr]; h = f2bf(f); h4.y = h; l4.y = f2bf(f - bf2f(h));
    f = t[cc + 2][q * 16 + rr]; h = f2bf(f); h4.z = h; l4.z = f2bf(f - bf2f(h));
    f = t[cc + 3][q * 16 + rr]; h = f2bf(f); h4.w = h; l4.w = f2bf(f - bf2f(h));
    *(ushort4*)(oh + obase + (size_t)oc * R + od) = h4;
    *(ushort4*)(ol + obase + (size_t)oc * R + od) = l4;
  }
}

// ---------------------------------------------------------------------------
// 6) Split-bf16 MFMA GEMM, pipelined. C[M,N] = A[M,K]*B[N,K]^T.
//    128x128 tile, BK=32, 4 waves (2x2), double-buffered LDS (2x32KB),
//    depth-2 prefetch, raw s_barrier + counted vmcnt(8). Each wave's 8
//    staging loads/tile cover slices of all 4 planes, so per-wave vmcnt(8)
//    + barrier => whole tile landed (cross-wave safe).
//    EPI=0: gelu(acc+b1) -> LDS bounce -> ushort4 hi/lo stores.
//    EPI=1: atomicAdd((acc [+bias if kc==0])*w) into oute; K-split KSPLIT.
// ---------------------------------------------------------------------------
template<int NN, int FULLK, int CHUNKK, int EPI, int KSPLIT>
__global__ __launch_bounds__(256, 2) void gemm_mfma(
    const u16* __restrict__ Ah, const u16* __restrict__ Al,
    const u16* __restrict__ Bh, const u16* __restrict__ Bl,
    const float* __restrict__ bias,
    u16* __restrict__ Oh, u16* __restrict__ Ol,
    float* __restrict__ Oe, const float* __restrict__ wslot,
    int e_off)
{
  constexpr int NT = CHUNKK / 32;
  // LDS: stage = 2 bufs x 4 planes x 8KB = 64KB; EPI0 epilogue bounce
  // 4 waves x 64x65 f32 = 65KB (union). 2 blocks/CU either way.
  constexpr int SMEM = (EPI == 0) ? (4 * 64 * 65 * 4) : 65536;
  __shared__ __align__(16) char smem[SMEM];
  u16* st = (u16*)smem;

  const int tid = threadIdx.x, lane = tid & 63, wid = tid >> 6;
  const int wm = wid >> 1, wn = wid & 1;

  // bijective XCD chunk swizzle (m204): each XCD gets a contiguous run of
  // linear block ids (all-M x few-N of one z) -> B panels L2-resident.
  const int gx = gridDim.x, gy = gridDim.y;
  const int nwg = gx * gy * gridDim.z;
  int wg = blockIdx.x + gx * (blockIdx.y + gy * blockIdx.z);
  {
    const int xcd = wg & 7, rest = wg >> 3;
    const int q = nwg >> 3, r = nwg & 7;
    wg = (xcd < r ? xcd * (q + 1) : r * (q + 1) + (xcd - r) * q) + rest;
  }
  const int bx = wg % gx; int t2 = wg / gx;
  const int by = t2 % gy; const int bzz = t2 / gy;
  const int zi = bzz / KSPLIT, kc = bzz % KSPLIT;
  const int m0 = bx * 128, n0 = by * 128;
  const int eg = e_off + zi;
  const size_t kbase = (size_t)kc * CHUNKK;

  const size_t a0 = ((size_t)zi * CAP + m0) * FULLK + kbase;
  const size_t b0 = ((size_t)zi * NN  + n0) * FULLK + kbase;
  const u16* gsrc[4] = {Ah + a0, Al + a0, Bh + b0, Bl + b0};

  // stage tile kt into buffer cb: 8 rounds x 256 threads x 16B = 32KB.
  // linear slot s = i*256+tid: plane = s>>9, q = s&511 (row = q>>2, slot = q&3,
  // source slot XOR-swizzled so swizzled frag reads see linear k).
  auto STAGE = [&](int cb, int kt) {
#pragma unroll
    for (int i = 0; i < 8; i++) {
      const int s   = i * 256 + tid;
      const int p   = s >> 9;
      const int q   = s & 511;
      const int row = q >> 2;
      const int gsl = (q & 3) ^ ((row >> 2) & 3);
      const u16* src = gsrc[p] + (size_t)row * FULLK + kt * 32 + gsl * 8;
      const int q0  = (i * 256 + (tid & 192)) & 511;   // wave-uniform base slot
      u16* dst = st + (((cb << 2) + p) << 12) + q0 * 8;
      gload16(src, dst);
    }
  };

  f32x4 acc[4][4] = {};

  STAGE(0, 0);
  STAGE(1, 1);
  int cur = 0;
  for (int kt = 0; kt < NT; ++kt) {
    // wait: my 8 oldest loads (= my slices of buf[cur]) landed; every wave
    // does the same -> after barrier the whole tile is resident. 8 newer
    // loads (next tile) stay in flight across the barrier (no drain).
    if (kt != NT - 1) { asm volatile("s_waitcnt vmcnt(8)" ::: "memory"); }
    else             { asm volatile("s_waitcnt vmcnt(0)" ::: "memory"); }
    __builtin_amdgcn_s_barrier();

    const u16* pAh = st + (((cur << 2) + 0) << 12);
    const u16* pAl = st + (((cur << 2) + 1) << 12);
    const u16* pBh = st + (((cur << 2) + 2) << 12);
    const u16* pBl = st + (((cur << 2) + 3) << 12);
    bf16x8 afh[4], afl[4], bfh[4], bfl[4];
#pragma unroll
    for (int mf = 0; mf < 4; mf++) {
      const int r = wm * 64 + mf * 16 + (lane & 15);
      const int off = r * 32 + (((lane >> 4) ^ ((r >> 2) & 3)) << 3);
      afh[mf] = *(const bf16x8*)(pAh + off);
      afl[mf] = *(const bf16x8*)(pAl + off);
    }
#pragma unroll
    for (int nf = 0; nf < 4; nf++) {
      const int r = wn * 64 + nf * 16 + (lane & 15);
      const int off = r * 32 + (((lane >> 4) ^ ((r >> 2) & 3)) << 3);
      bfh[nf] = *(const bf16x8*)(pBh + off);
      bfl[nf] = *(const bf16x8*)(pBl + off);
    }
    __builtin_amdgcn_s_setprio(1);
#pragma unroll
    for (int mf = 0; mf < 4; mf++) {
#pragma unroll
      for (int nf = 0; nf < 4; nf++) {
        acc[mf][nf] = __builtin_amdgcn_mfma_f32_16x16x32_bf16(afh[mf], bfh[nf], acc[mf][nf], 0, 0, 0);
        acc[mf][nf] = __builtin_amdgcn_mfma_f32_16x16x32_bf16(afh[mf], bfl[nf], acc[mf][nf], 0, 0, 0);
        acc[mf][nf] = __builtin_amdgcn_mfma_f32_16x16x32_bf16(afl[mf], bfh[nf], acc[mf][nf], 0, 0, 0);
      }
    }
    __builtin_amdgcn_s_setprio(0);
    __builtin_amdgcn_sched_barrier(0);
    __builtin_amdgcn_s_barrier();      // all waves done reading buf[cur]
    __builtin_amdgcn_sched_barrier(0);
    if (kt + 2 < NT) STAGE(cur, kt + 2);   // overwrite cur with tile kt+2
    cur ^= 1;
  }

  if constexpr (EPI == 0) {
    // bounce acc through padded LDS (per-wave private 64x65 f32 region),
    // read back row-major, gelu, split, ushort4 stores (coalesced 128B/row).
    float* epi = (float*)smem + wid * (64 * 65);
#pragma unroll
    for (int mf = 0; mf < 4; mf++)
#pragma unroll
      for (int nf = 0; nf < 4; nf++)
#pragma unroll
        for (int r = 0; r < 4; r++)
          epi[(mf * 16 + (lane >> 4) * 4 + r) * 65 + nf * 16 + (lane & 15)] = acc[mf][nf][r];
    const float* brow = bias + (size_t)eg * NN + n0 + wn * 64;
#pragma unroll
    for (int it = 0; it < 16; ++it) {
      const int rr = it * 4 + (lane >> 4);     // row within wave tile
      const int cc = (lane & 15) * 4;          // col within wave tile
      float4 v = *(const float4*)&epi[rr * 65 + cc];
      const float4 bv = *(const float4*)(brow + cc);
      ushort4 h4, l4; u16 h; float g;
      g = v.x + bv.x; g = 0.5f * g * (1.0f + erff(g * 0.70710678118654752f));
      h = f2bf(g); h4.x = h; l4.x = f2bf(g - bf2f(h));
      g = v.y + bv.y; g = 0.5f * g * (1.0f + erff(g * 0.70710678118654752f));
      h = f2bf(g); h4.y = h; l4.y = f2bf(g - bf2f(h));
      g = v.z + bv.z; g = 0.5f * g * (1.0f + erff(g * 0.70710678118654752f));
      h = f2bf(g); h4.z = h; l4.z = f2bf(g - bf2f(h));
      g = v.w + bv.w; g = 0.5f * g * (1.0f + erff(g * 0.70710678118654752f));
      h = f2bf(g); h4.w = h; l4.w = f2bf(g - bf2f(h));
      const size_t o = ((size_t)zi * CAP + m0 + wm * 64 + rr) * NN + n0 + wn * 64 + cc;
      *(ushort4*)(Oh + o) = h4;
      *(ushort4*)(Ol + o) = l4;
    }
  } else {
    // K-split partial: atomicAdd (acc [+bias on chunk 0]) * w into oute.
#pragma unroll
    for (int mf = 0; mf < 4; mf++) {
#pragma unroll
      for (int nf = 0; nf < 4; nf++) {
        const int col = n0 + wn * 64 + nf * 16 + (lane & 15);
        const float bv = (kc == 0) ? bias[(size_t)eg * NN + col] : 0.0f;
#pragma unroll
        for (int r = 0; r < 4; r++) {
          const int row = m0 + wm * 64 + mf * 16 + (lane >> 4) * 4 + r;
          const int slot = eg * CAP + row;
          const float contrib = (acc[mf][nf][r] + bv) * wslot[slot];
          atomicAdd(&Oe[(size_t)slot * NN + col], contrib);
        }
      }
    }
  }
}

// ---------------------------------------------------------------------------
// 7) Combine (<=2 slot rows per token, deterministic order) + LayerNorm.
// ---------------------------------------------------------------------------
__global__ __launch_bounds__(256) void combine_ln(
    const float* __restrict__ oute, const int* __restrict__ s_of_t,
    const float* __restrict__ gam, const float* __restrict__ bet,
    float* __restrict__ out)
{
  const int n = blockIdx.x, tid = threadIdx.x, lane = tid & 63, wid = tid >> 6;
  __shared__ float sred[4];
  const int s0 = s_of_t[2 * n], s1 = s_of_t[2 * n + 1];
  const int idx = tid * 4;
  float y0 = 0.f, y1 = 0.f, y2 = 0.f, y3 = 0.f;
  if (s0 >= 0) {
    const float4 a = *(const float4*)(oute + (size_t)s0 * DOUT + idx);
    y0 = a.x; y1 = a.y; y2 = a.z; y3 = a.w;
  }
  if (s1 >= 0) {
    const float4 a = *(const float4*)(oute + (size_t)s1 * DOUT + idx);
    y0 += a.x; y1 += a.y; y2 += a.z; y3 += a.w;
  }
  float ssum = y0 + y1 + y2 + y3;
  for (int o = 32; o; o >>= 1) ssum += __shfl_down(ssum, o, 64);
  if (lane == 0) sred[wid] = ssum;
  __syncthreads();
  const float mu = (sred[0] + sred[1] + sred[2] + sred[3]) * (1.f / DOUT);
  __syncthreads();
  const float d0 = y0 - mu, d1 = y1 - mu, d2 = y2 - mu, d3 = y3 - mu;
  float sq = d0 * d0 + d1 * d1 + d2 * d2 + d3 * d3;
  for (int o = 32; o; o >>= 1) sq += __shfl_down(sq, o, 64);
  if (lane == 0) sred[wid] = sq;
  __syncthreads();
  const float var = (sred[0] + sred[1] + sred[2] + sred[3]) * (1.f / DOUT);
  const float inv = 1.0f / sqrtf(var + 1e-5f);
  float4 o4;
  o4.x = d0 * inv * gam[idx + 0] + bet[idx + 0];
  o4.y = d1 * inv * gam[idx + 1] + bet[idx + 1];
  o4.z = d2 * inv * gam[idx + 2] + bet[idx + 2];
  o4.w = d3 * inv * gam[idx + 3] + bet[idx + 3];
  *(float4*)(out + (size_t)n * DOUT + idx) = o4;
}

// ---------------------------------------------------------------------------
extern "C" void kernel_launch(void* const* d_in, const int* in_sizes, int n_in,
                              void* d_out, int out_size, void* d_ws, size_t ws_size,
                              hipStream_t stream)
{
  const float* x   = (const float*)d_in[0];
  const float* rw  = (const float*)d_in[1];
  const float* rb  = (const float*)d_in[2];
  const float* w1  = (const float*)d_in[3];
  const float* b1  = (const float*)d_in[4];
  const float* w2  = (const float*)d_in[5];
  const float* b2  = (const float*)d_in[6];
  const float* lng = (const float*)d_in[7];
  const float* lnb = (const float*)d_in[8];
  float* out = (float*)d_out;

  char* base = (char*)d_ws;
  size_t off = 0;
  auto alloc = [&](size_t bytes) -> void* {
    void* p = base + off;
    off = (off + bytes + 255) & ~(size_t)255;
    return p;
  };
  int*   topi = (int*)  alloc((size_t)NTOK * TOPK * 4);
  float* topv = (float*)alloc((size_t)NTOK * TOPK * 4);
  u32*   tb   = (u32*)  alloc(NE * 4);
  int*   ntie = (int*)  alloc(NE * 4);
  int*   cnt  = (int*)  alloc(NE * 4);
  int*   tok  = (int*)  alloc((size_t)NE * CAP * 4);
  float* wsl  = (float*)alloc((size_t)NE * CAP * 4);
  int*   soft = (int*)  alloc((size_t)NTOK * TOPK * 4);
  u16*   Xh   = (u16*)  alloc((size_t)NE * CAP * DIN * 2);
  u16*   Xl   = (u16*)  alloc((size_t)NE * CAP * DIN * 2);
  float* oute = (float*)alloc((size_t)NE * CAP * DOUT * 4);
  const size_t fixed = off;

  const size_t perE = 2 * ((size_t)DIN * HID * 2) + 2 * ((size_t)HID * DOUT * 2)
                    + 2 * ((size_t)CAP * HID * 2);
  int G = 1;
  for (int g = 8; g >= 1; g >>= 1) {
    if (fixed + (size_t)g * perE + 8192 <= ws_size) { G = g; break; }
  }
  u16* W1Th = (u16*)alloc((size_t)G * DIN * HID * 2);
  u16* W1Tl = (u16*)alloc((size_t)G * DIN * HID * 2);
  u16* W2Th = (u16*)alloc((size_t)G * HID * DOUT * 2);
  u16* W2Tl = (u16*)alloc((size_t)G * HID * DOUT * 2);
  u16* hh   = (u16*)alloc((size_t)G * CAP * HID * 2);
  u16* hl   = (u16*)alloc((size_t)G * CAP * HID * 2);

  router_topk<<<NTOK, 256, 0, stream>>>(x, rw, rb, topi, topv);
  select_caps<<<NE, 256, 0, stream>>>(topi, topv, tb, ntie);
  assign_slots<<<NE, 256, 0, stream>>>(topi, topv, tb, ntie, cnt, tok, wsl, soft);
  gather_x<<<NE * CAP, 256, 0, stream>>>(x, tok, cnt, Xh, Xl);
  hipMemsetAsync(oute, 0, (size_t)NE * CAP * DOUT * 4, stream);   // K-split accumulator

  for (int g0 = 0; g0 < NE; g0 += G) {
    transpose_split<<<dim3(HID / 64, DIN / 64, G), 256, 0, stream>>>(w1, W1Th, W1Tl, DIN, HID, g0);
    transpose_split<<<dim3(DOUT / 64, HID / 64, G), 256, 0, stream>>>(w2, W2Th, W2Tl, HID, DOUT, g0);
    gemm_mfma<HID, DIN, DIN, 0, 1><<<dim3(CAP / 128, HID / 128, G), 256, 0, stream>>>(
        Xh + (size_t)g0 * CAP * DIN, Xl + (size_t)g0 * CAP * DIN,
        W1Th, W1Tl, b1, hh, hl, nullptr, nullptr, g0);
    gemm_mfma<DOUT, HID, 1024, 1, 4><<<dim3(CAP / 128, DOUT / 128, G * 4), 256, 0, stream>>>(
        hh, hl, W2Th, W2Tl, b2, nullptr, nullptr, oute, wsl, g0);
  }

  combine_ln<<<NTOK, 256, 0, stream>>>(oute, soft, lng, lnb, out);
}